// Round 1
// baseline (107.664 us; speedup 1.0000x reference)
//
#include <hip/hip_runtime.h>

// Problem: x (32768, 4096) f32, W (4096, 4096) f32 (hidden, input).
// reference: sum over h of (x @ W^T) * 1.0  ==  x @ colsum_h(W) * 1.0
// -> column-sum W (sum over rows h at fixed input index i), then matvec.

#define BATCH   32768
#define HIDDEN  4096
#define INDIM   4096
#define ROWCHUNKS 64
#define ROWS_PER_CHUNK (HIDDEN / ROWCHUNKS)   // 64

// ---------------------------------------------------------------------------
// Kernel 1: partial column sums. grid (4, ROWCHUNKS), block 256.
// Each thread owns 4 consecutive columns (one float4), sums 64 rows.
// partial[chunk][col] laid out [ROWCHUNKS][INDIM] floats in d_ws.
__global__ void __launch_bounds__(256)
colsum_partial_kernel(const float* __restrict__ W, float* __restrict__ partial) {
    const int col4 = blockIdx.x * 256 + threadIdx.x;      // float4 index, 0..1023
    const int row0 = blockIdx.y * ROWS_PER_CHUNK;
    const float4* Wv = reinterpret_cast<const float4*>(W);
    float4 acc = make_float4(0.f, 0.f, 0.f, 0.f);
#pragma unroll 8
    for (int r = 0; r < ROWS_PER_CHUNK; ++r) {
        float4 v = Wv[(size_t)(row0 + r) * (INDIM / 4) + col4];
        acc.x += v.x; acc.y += v.y; acc.z += v.z; acc.w += v.w;
    }
    reinterpret_cast<float4*>(partial)[(size_t)blockIdx.y * (INDIM / 4) + col4] = acc;
}

// ---------------------------------------------------------------------------
// Kernel 2: reduce ROWCHUNKS partials -> w_sum (INDIM floats). grid 4, block 256.
__global__ void __launch_bounds__(256)
colsum_final_kernel(const float* __restrict__ partial, float* __restrict__ wsum) {
    const int col4 = blockIdx.x * 256 + threadIdx.x;      // 0..1023
    const float4* Pv = reinterpret_cast<const float4*>(partial);
    float4 acc = make_float4(0.f, 0.f, 0.f, 0.f);
#pragma unroll 8
    for (int p = 0; p < ROWCHUNKS; ++p) {
        float4 v = Pv[(size_t)p * (INDIM / 4) + col4];
        acc.x += v.x; acc.y += v.y; acc.z += v.z; acc.w += v.w;
    }
    reinterpret_cast<float4*>(wsum)[col4] = acc;
}

// ---------------------------------------------------------------------------
// Kernel 3: out[b] = dot(x[b,:], w_sum) * scale. One wave (64 lanes) per row.
// 256 threads/block = 4 rows/block -> 8192 blocks.
// Lane l, step k reads float4 index k*64+l: wave covers 1 KiB contiguous/step.
__global__ void __launch_bounds__(256)
matvec_kernel(const float* __restrict__ x, const float* __restrict__ wsum,
              float* __restrict__ out) {
    const int gtid = blockIdx.x * 256 + threadIdx.x;
    const int row  = gtid >> 6;          // global wave id
    const int lane = threadIdx.x & 63;

    const float4* xv = reinterpret_cast<const float4*>(x) + (size_t)row * (INDIM / 4);
    const float4* wv = reinterpret_cast<const float4*>(wsum);

    float acc = 0.f;
#pragma unroll
    for (int k = 0; k < INDIM / 4 / 64; ++k) {           // 16 steps
        const int idx = k * 64 + lane;
        float4 xr = xv[idx];
        float4 wr = wv[idx];                              // 16 KiB hot, L1-served
        acc += xr.x * wr.x + xr.y * wr.y + xr.z * wr.z + xr.w * wr.w;
    }

    // wave-64 butterfly reduce
#pragma unroll
    for (int off = 32; off > 0; off >>= 1)
        acc += __shfl_down(acc, off, 64);

    if (lane == 0)
        out[row] = acc * 1.0f;   // COMBINED_SCALE = 2.0/2.0
}

// ---------------------------------------------------------------------------
extern "C" void kernel_launch(void* const* d_in, const int* in_sizes, int n_in,
                              void* d_out, int out_size, void* d_ws, size_t ws_size,
                              hipStream_t stream) {
    const float* x = (const float*)d_in[0];        // (32768, 4096)
    const float* W = (const float*)d_in[1];        // (4096, 4096)
    float* out = (float*)d_out;                    // 32768 floats

    // workspace layout: [0, ROWCHUNKS*INDIM) partials, then INDIM for w_sum
    float* partial = (float*)d_ws;
    float* wsum    = partial + (size_t)ROWCHUNKS * INDIM;

    colsum_partial_kernel<<<dim3(INDIM / 4 / 256, ROWCHUNKS), 256, 0, stream>>>(W, partial);
    colsum_final_kernel<<<dim3(INDIM / 4 / 256), 256, 0, stream>>>(partial, wsum);
    matvec_kernel<<<dim3(BATCH / 4), 256, 0, stream>>>(x, wsum, out);
}

// Round 2
// 100.719 us; speedup vs baseline: 1.0690x; 1.0690x over previous
//
#include <hip/hip_runtime.h>

// out[b] = sum_h sum_i x[b,i] W[h,i] * 1.0  ==  dot(x[b,:], colsum_h(W))
// Phase 1: partial column sums of W.  Phase 2: reduce partials -> wsum.
// Phase 3: matvec out = x . wsum  (pure stream over x, wsum staged in LDS).

#define BATCH   32768
#define HIDDEN  4096
#define INDIM   4096
#define ROWCHUNKS 64
#define ROWS_PER_CHUNK (HIDDEN / ROWCHUNKS)   // 64

typedef float f32x4 __attribute__((ext_vector_type(4)));

// ---------------------------------------------------------------------------
// Kernel 1: partial column sums. grid (4, ROWCHUNKS), block 256.
// Thread owns one float4 column-group, sums 64 rows (unroll 16 -> deep queue).
__global__ void __launch_bounds__(256)
colsum_partial_kernel(const float* __restrict__ W, float* __restrict__ partial) {
    const int col4 = blockIdx.x * 256 + threadIdx.x;      // 0..1023
    const int row0 = blockIdx.y * ROWS_PER_CHUNK;
    const f32x4* Wv = reinterpret_cast<const f32x4*>(W);
    f32x4 acc = {0.f, 0.f, 0.f, 0.f};
#pragma unroll 16
    for (int r = 0; r < ROWS_PER_CHUNK; ++r) {
        f32x4 v = Wv[(size_t)(row0 + r) * (INDIM / 4) + col4];
        acc += v;
    }
    reinterpret_cast<f32x4*>(partial)[(size_t)blockIdx.y * (INDIM / 4) + col4] = acc;
}

// ---------------------------------------------------------------------------
// Kernel 2: reduce ROWCHUNKS partials -> wsum. One thread per column.
// grid 16, block 256; consecutive threads read consecutive addresses.
__global__ void __launch_bounds__(256)
colsum_final_kernel(const float* __restrict__ partial, float* __restrict__ wsum) {
    const int col = blockIdx.x * 256 + threadIdx.x;       // 0..4095
    float acc = 0.f;
#pragma unroll 8
    for (int p = 0; p < ROWCHUNKS; ++p)
        acc += partial[(size_t)p * INDIM + col];
    wsum[col] = acc;
}

// ---------------------------------------------------------------------------
// Kernel 3: out[b] = dot(x[b,:], wsum). One wave per row, 4 rows/block.
// wsum staged in LDS (16 KiB) so the hot loop issues ONLY streaming x loads.
__global__ void __launch_bounds__(256)
matvec_kernel(const float* __restrict__ x, const float* __restrict__ wsum,
              float* __restrict__ out) {
    __shared__ f32x4 wlds[INDIM / 4];                     // 1024 * 16B = 16 KiB
    const int tid = threadIdx.x;
    const f32x4* wv = reinterpret_cast<const f32x4*>(wsum);
#pragma unroll
    for (int j = 0; j < 4; ++j)
        wlds[j * 256 + tid] = wv[j * 256 + tid];
    __syncthreads();

    const int row  = (blockIdx.x * 256 + tid) >> 6;       // global wave id
    const int lane = tid & 63;
    const f32x4* xv = reinterpret_cast<const f32x4*>(x) + (size_t)row * (INDIM / 4);

    float acc = 0.f;
#pragma unroll
    for (int k = 0; k < INDIM / 4 / 64; ++k) {            // 16 steps
        const int idx = k * 64 + lane;
        f32x4 xr = __builtin_nontemporal_load(&xv[idx]);  // zero-reuse stream
        f32x4 wr = wlds[idx];                             // LDS, conflict-free
        acc += xr.x * wr.x + xr.y * wr.y + xr.z * wr.z + xr.w * wr.w;
    }

    // wave-64 butterfly reduce
#pragma unroll
    for (int off = 32; off > 0; off >>= 1)
        acc += __shfl_down(acc, off, 64);

    if (lane == 0)
        out[row] = acc * 1.0f;   // COMBINED_SCALE = 2.0/2.0
}

// ---------------------------------------------------------------------------
extern "C" void kernel_launch(void* const* d_in, const int* in_sizes, int n_in,
                              void* d_out, int out_size, void* d_ws, size_t ws_size,
                              hipStream_t stream) {
    const float* x = (const float*)d_in[0];        // (32768, 4096)
    const float* W = (const float*)d_in[1];        // (4096, 4096)
    float* out = (float*)d_out;                    // 32768 floats

    float* partial = (float*)d_ws;                               // 1 MiB
    float* wsum    = partial + (size_t)ROWCHUNKS * INDIM;        // 16 KiB

    colsum_partial_kernel<<<dim3(INDIM / 4 / 256, ROWCHUNKS), 256, 0, stream>>>(W, partial);
    colsum_final_kernel<<<dim3(INDIM / 256), 256, 0, stream>>>(partial, wsum);
    matvec_kernel<<<dim3(BATCH / 4), 256, 0, stream>>>(x, wsum, out);
}